// Round 5
// baseline (708.183 us; speedup 1.0000x reference)
//
#include <hip/hip_runtime.h>

// Shapes
// B=8, NF=64, FIN=192, FH=128, FOUT=64, LAT=512, P_TOTAL=61824
// dyn param offsets: w_in 0, b_in 24576, w_mid 24704, b_mid 41088,
//                    w_out 41216, b_out 49408, w_sk 49472, b_sk 61760

#define BATCH 8
#define PT 61824
#define HNB 16   // head mega-kernel block count

typedef __attribute__((ext_vector_type(8))) short bf16x8;
typedef __attribute__((ext_vector_type(4))) float f32x4;

__device__ __forceinline__ float lrelu(float v) { return v > 0.f ? v : 0.2f * v; }

__device__ __forceinline__ short f2bf(float f) {
    union { float fv; unsigned u; } v; v.fv = f;
    return (short)((v.u + 0x8000u) >> 16);  // round half away from zero (2 ops)
}

// software grid barrier: all HNB blocks co-resident (16 blocks, idle GPU)
__device__ __forceinline__ void grid_barrier(int* bar, int gen) {
    __threadfence();
    __syncthreads();
    if (threadIdx.x == 0) {
        atomicAdd(bar, 1);
        int target = gen * HNB;
        while (__hip_atomic_load(bar, __ATOMIC_RELAXED, __HIP_MEMORY_SCOPE_AGENT) < target)
            __builtin_amdgcn_s_sleep(1);
        __threadfence();
    }
    __syncthreads();
}

// ---------------------------------------------------------------------------
// Kernel 1: hypernetwork  dyn[b][p] = sum_k inj[b][k] * hyp_w[k][p] + hyp_b[p]
// ---------------------------------------------------------------------------
__global__ __launch_bounds__(256) void hyper_kernel(
    const float* __restrict__ inj, const float* __restrict__ hw,
    const float* __restrict__ hb, float* __restrict__ dyn,
    short* __restrict__ dyn16)
{
    __shared__ float s_l[512 * 8];  // transposed: s_l[k*8 + b]
    int t = threadIdx.x;
    for (int i = t; i < 4096; i += 256) {
        int b = i >> 9, k = i & 511;
        s_l[k * 8 + b] = inj[i];
    }
    __syncthreads();
    int p = blockIdx.x * 256 + t;
    if (p >= PT) return;
    float acc[8];
#pragma unroll
    for (int b = 0; b < 8; ++b) acc[b] = 0.f;
    for (int k = 0; k < 512; ++k) {
        float w = hw[(size_t)k * PT + p];
        float4 a0 = *(const float4*)&s_l[k * 8];
        float4 a1 = *(const float4*)&s_l[k * 8 + 4];
        acc[0] += a0.x * w; acc[1] += a0.y * w; acc[2] += a0.z * w; acc[3] += a0.w * w;
        acc[4] += a1.x * w; acc[5] += a1.y * w; acc[6] += a1.z * w; acc[7] += a1.w * w;
    }
    float bias = hb[p];
#pragma unroll
    for (int b = 0; b < 8; ++b) {
        float v = acc[b] + bias;
        dyn[(size_t)b * PT + p] = v;
        dyn16[(size_t)b * PT + p] = f2bf(v);
    }
}

// ---------------------------------------------------------------------------
// Kernel 2: stem = conv1x1(x, in_w, in_b) then res_block(inrb) -> emb0
// ---------------------------------------------------------------------------
__global__ __launch_bounds__(256) void stem_kernel(
    const float* __restrict__ x, const float* __restrict__ in_w,
    const float* __restrict__ in_b,
    const float* __restrict__ w0, const float* __restrict__ b0,
    const float* __restrict__ w1, const float* __restrict__ b1,
    float* __restrict__ out0)
{
    const int HW = 128 * 128;
    __shared__ float s_t0[64 * 68];
    __shared__ float s_v[64 * 68];
    const int tilesPer = HW / 64;  // 256
    const int b = blockIdx.x / tilesPer;
    const int tile = blockIdx.x - b * tilesPer;
    const int pix0 = tile * 64;
    const int t = threadIdx.x;

    for (int job = t; job < 64 * 64; job += 256) {
        int p = job & 63, c = job >> 6;
        const float* xb = x + (size_t)b * 3 * HW + pix0 + p;
        float v = in_b[c] + xb[0] * in_w[c * 3] + xb[HW] * in_w[c * 3 + 1]
                + xb[2 * HW] * in_w[c * 3 + 2];
        s_t0[p * 68 + c] = v;
        s_v[p * 68 + c] = lrelu(v);
    }
    __syncthreads();

    const int o = t & 63, g = t >> 6;
    {
        float acc[16];
#pragma unroll
        for (int p = 0; p < 16; ++p) acc[p] = 0.f;
        const float* wr = w0 + o * 64;
        for (int k4 = 0; k4 < 16; ++k4) {
            float4 wv = ((const float4*)wr)[k4];
#pragma unroll
            for (int p = 0; p < 16; ++p) {
                float4 uv = *(const float4*)&s_v[(g * 16 + p) * 68 + k4 * 4];
                acc[p] += wv.x * uv.x + wv.y * uv.y + wv.z * uv.z + wv.w * uv.w;
            }
        }
        __syncthreads();
        float bi = b0[o];
#pragma unroll
        for (int p = 0; p < 16; ++p) s_v[(g * 16 + p) * 68 + o] = lrelu(acc[p] + bi);
    }
    __syncthreads();
    {
        float acc[16];
#pragma unroll
        for (int p = 0; p < 16; ++p) acc[p] = 0.f;
        const float* wr = w1 + o * 64;
        for (int k4 = 0; k4 < 16; ++k4) {
            float4 wv = ((const float4*)wr)[k4];
#pragma unroll
            for (int p = 0; p < 16; ++p) {
                float4 uv = *(const float4*)&s_v[(g * 16 + p) * 68 + k4 * 4];
                acc[p] += wv.x * uv.x + wv.y * uv.y + wv.z * uv.z + wv.w * uv.w;
            }
        }
        float bi = b1[o];
        float* ob = out0 + ((size_t)b * 64 + o) * HW;
#pragma unroll
        for (int p = 0; p < 16; ++p) {
            int pix = pix0 + g * 16 + p;
            ob[pix] = s_t0[(g * 16 + p) * 68 + o] + 0.1f * (acc[p] + bi);
        }
    }
}

// ---------------------------------------------------------------------------
// Kernel 3: fused iteration via MFMA, templated on tile size (MT m-tiles of 16 px)
// ---------------------------------------------------------------------------
template<int MT>
__global__ __launch_bounds__(256) void iter_kernel(
    const float* __restrict__ cur, const float* __restrict__ dynf,
    const short* __restrict__ dynb, const float* __restrict__ leak_p,
    float* __restrict__ y, int S, int sh)
{
    constexpr int PX = MT * 16;
    constexpr int SY = (MT == 4) ? 68 : 20;   // fp32 out stride (words)
    __shared__ short s_s[PX * 200];   // bf16 sobel [pix][192], stride 200
    __shared__ short s_h[PX * 136];   // bf16 h1 then h2 [pix][128], stride 136
    float* s_y = (float*)s_s;         // fp32 d [o][px]

    const int HW = S * S;
    const int tilesPer = HW / PX;
    const int b = blockIdx.x / tilesPer;
    const int tile = blockIdx.x - b * tilesPer;
    const int pix0 = tile * PX;
    const int t = threadIdx.x;
    const int l = t & 63, w = t >> 6;
    const int lp = l & 15, lq = l >> 4;
    const float* base = cur + (size_t)b * 64 * HW;

    // ---- phase 0: sin_sobel via shuffles ----
    {
        const int p = (MT == 4) ? (lp + 16 * w) : lp;
        const int gpx = pix0 + p;
        const int row = gpx >> sh;
        const int x = gpx & (S - 1);
        const bool rm = (row > 0), rp = (row < S - 1);
        const bool le = (lp == 0) && (x > 0);
        const bool re = (lp == 15) && (x < S - 1);
        const int iters = (MT == 4) ? 8 : 2;
        int* s32 = (int*)s_s;
        for (int i = 0; i < iters; ++i) {
            const int cp = (MT == 4) ? (lq + 4 * i) : (lq + 4 * w + 16 * i);
            unsigned pk_id = 0, pk_sx = 0, pk_sy = 0;
#pragma unroll
            for (int cc = 0; cc < 2; ++cc) {
                const int c = 2 * cp + cc;
                const float* ch = base + (size_t)c * HW + row * S;
                float vm = rm ? ch[x - S] : 0.f;
                float v0 = ch[x];
                float vp = rp ? ch[x + S] : 0.f;
                float elm = 0.f, el0 = 0.f, elp = 0.f, erm = 0.f, er0 = 0.f, erp = 0.f;
                if (le) { elm = rm ? ch[x - 1 - S] : 0.f; el0 = ch[x - 1]; elp = rp ? ch[x - 1 + S] : 0.f; }
                if (re) { erm = rm ? ch[x + 1 - S] : 0.f; er0 = ch[x + 1]; erp = rp ? ch[x + 1 + S] : 0.f; }
                float Lm = __shfl(vm, l - 1), L0 = __shfl(v0, l - 1), Lp = __shfl(vp, l - 1);
                float Rm = __shfl(vm, l + 1), R0 = __shfl(v0, l + 1), Rp = __shfl(vp, l + 1);
                if (lp == 0)  { Lm = elm; L0 = el0; Lp = elp; }
                if (lp == 15) { Rm = erm; R0 = er0; Rp = erp; }
                if (x == 0)     { Lm = 0.f; L0 = 0.f; Lp = 0.f; }
                if (x == S - 1) { Rm = 0.f; R0 = 0.f; Rp = 0.f; }
                float sx = (Lm - Rm + 2.f * (L0 - R0) + Lp - Rp) * 0.125f;
                float sy = (Lm + 2.f * vm + Rm - Lp - 2.f * vp - Rp) * 0.125f;
                unsigned hid = (unsigned short)f2bf(v0);
                unsigned hsx = (unsigned short)f2bf(sx);
                unsigned hsy = (unsigned short)f2bf(sy);
                pk_id |= hid << (16 * cc);
                pk_sx |= hsx << (16 * cc);
                pk_sy |= hsy << (16 * cc);
            }
            s32[p * 100 + cp] = (int)pk_id;
            s32[p * 100 + 32 + cp] = (int)pk_sx;
            s32[p * 100 + 64 + cp] = (int)pk_sy;
        }
    }
    __syncthreads();

    const short* wb = dynb + (size_t)b * PT;
    const float* pf = dynf + (size_t)b * PT;
    const f32x4 z4 = {0.f, 0.f, 0.f, 0.f};

    // ---- phase 1: h1 = act(w_in * s + b_in)   O=128 (2 ntiles/wave), K=192 ----
    {
        f32x4 acc[2][MT];
#pragma unroll
        for (int n = 0; n < 2; ++n)
#pragma unroll
            for (int mt = 0; mt < MT; ++mt) acc[n][mt] = z4;
        for (int k = 0; k < 6; ++k) {
            bf16x8 a[MT];
#pragma unroll
            for (int mt = 0; mt < MT; ++mt)
                a[mt] = *(const bf16x8*)&s_s[(mt * 16 + lp) * 200 + k * 32 + lq * 8];
#pragma unroll
            for (int n = 0; n < 2; ++n) {
                int o = (w * 2 + n) * 16 + lp;
                bf16x8 bb = *(const bf16x8*)&wb[o * 192 + k * 32 + lq * 8];
#pragma unroll
                for (int mt = 0; mt < MT; ++mt)
                    acc[n][mt] = __builtin_amdgcn_mfma_f32_16x16x32_bf16(a[mt], bb, acc[n][mt], 0, 0, 0);
            }
        }
#pragma unroll
        for (int n = 0; n < 2; ++n) {
            int o = (w * 2 + n) * 16 + lp;
            float bi = pf[24576 + o];
#pragma unroll
            for (int mt = 0; mt < MT; ++mt)
#pragma unroll
                for (int r = 0; r < 4; ++r)
                    s_h[(mt * 16 + lq * 4 + r) * 136 + o] = f2bf(lrelu(acc[n][mt][r] + bi));
        }
    }
    __syncthreads();

    // ---- phase 2: h2 = act(w_mid * h1 + b_mid)   O=128, K=128 ----
    {
        f32x4 acc[2][MT];
#pragma unroll
        for (int n = 0; n < 2; ++n)
#pragma unroll
            for (int mt = 0; mt < MT; ++mt) acc[n][mt] = z4;
        for (int k = 0; k < 4; ++k) {
            bf16x8 a[MT];
#pragma unroll
            for (int mt = 0; mt < MT; ++mt)
                a[mt] = *(const bf16x8*)&s_h[(mt * 16 + lp) * 136 + k * 32 + lq * 8];
#pragma unroll
            for (int n = 0; n < 2; ++n) {
                int o = (w * 2 + n) * 16 + lp;
                bf16x8 bb = *(const bf16x8*)&wb[24704 + o * 128 + k * 32 + lq * 8];
#pragma unroll
                for (int mt = 0; mt < MT; ++mt)
                    acc[n][mt] = __builtin_amdgcn_mfma_f32_16x16x32_bf16(a[mt], bb, acc[n][mt], 0, 0, 0);
            }
        }
        __syncthreads();  // all h1 reads complete before overwrite
#pragma unroll
        for (int n = 0; n < 2; ++n) {
            int o = (w * 2 + n) * 16 + lp;
            float bi = pf[41088 + o];
#pragma unroll
            for (int mt = 0; mt < MT; ++mt)
#pragma unroll
                for (int r = 0; r < 4; ++r)
                    s_h[(mt * 16 + lq * 4 + r) * 136 + o] = f2bf(lrelu(acc[n][mt][r] + bi));
        }
    }
    __syncthreads();

    // ---- phase 3: d = w_out*h2 + w_sk*s + (b_out + b_sk)   O=64 ----
    {
        f32x4 acc[MT];
#pragma unroll
        for (int mt = 0; mt < MT; ++mt) acc[mt] = z4;
        int o = w * 16 + lp;
        for (int k = 0; k < 4; ++k) {
            bf16x8 bb = *(const bf16x8*)&wb[41216 + o * 128 + k * 32 + lq * 8];
#pragma unroll
            for (int mt = 0; mt < MT; ++mt) {
                bf16x8 a = *(const bf16x8*)&s_h[(mt * 16 + lp) * 136 + k * 32 + lq * 8];
                acc[mt] = __builtin_amdgcn_mfma_f32_16x16x32_bf16(a, bb, acc[mt], 0, 0, 0);
            }
        }
        for (int k = 0; k < 6; ++k) {
            bf16x8 bb = *(const bf16x8*)&wb[49472 + o * 192 + k * 32 + lq * 8];
#pragma unroll
            for (int mt = 0; mt < MT; ++mt) {
                bf16x8 a = *(const bf16x8*)&s_s[(mt * 16 + lp) * 200 + k * 32 + lq * 8];
                acc[mt] = __builtin_amdgcn_mfma_f32_16x16x32_bf16(a, bb, acc[mt], 0, 0, 0);
            }
        }
        float bi = pf[49408 + o] + pf[61760 + o];
        __syncthreads();  // all s_s reads complete before s_y (aliased) writes
#pragma unroll
        for (int mt = 0; mt < MT; ++mt)
#pragma unroll
            for (int r = 0; r < 4; ++r)
                s_y[o * SY + mt * 16 + lq * 4 + r] = acc[mt][r] + bi;
    }
    __syncthreads();

    // ---- phase 4: y = cur + leak * d  (coalesced fp32) ----
    {
        float lk = fminf(fmaxf(leak_p[0], 0.001f), 1000.f);
        if (MT == 4) {
#pragma unroll
            for (int v = 0; v < 4; ++v) {
                int idx = v * 1024 + t * 4;
                int o = idx >> 6, px = idx & 63;
                f32x4 sv = *(const f32x4*)&s_y[o * SY + px];
                const float* cb = cur + ((size_t)b * 64 + o) * HW + pix0 + px;
                float* yb = y + ((size_t)b * 64 + o) * HW + pix0 + px;
                f32x4 cv = *(const f32x4*)cb;
                *(f32x4*)yb = cv + lk * sv;
            }
        } else {
            int o = t >> 2, px = (t & 3) * 4;
            f32x4 sv = *(const f32x4*)&s_y[o * SY + px];
            const float* cb = cur + ((size_t)b * 64 + o) * HW + pix0 + px;
            float* yb = y + ((size_t)b * 64 + o) * HW + pix0 + px;
            f32x4 cv = *(const f32x4*)cb;
            *(f32x4*)yb = cv + lk * sv;
        }
    }
}

// ---------------------------------------------------------------------------
// Kernel 4: downsample = gauss3x3 (zero-pad) then 2x2 mean. Also zeroes the
// head grid-barrier counter (stream-ordered before head_kernel).
// ---------------------------------------------------------------------------
__global__ __launch_bounds__(256) void down_kernel(
    const float* __restrict__ yin, float* __restrict__ outp, int S, int total,
    int* __restrict__ bar)
{
    int idx = blockIdx.x * 256 + threadIdx.x;
    if (idx == 0) *bar = 0;
    if (idx >= total) return;
    const float ga = 0.60653065971263342f;
    const float gs = 1.f / ((1.f + 2.f * ga) * (1.f + 2.f * ga));
    float g1[3] = {ga, 1.f, ga};
    int S2 = S >> 1;
    int ox = idx % S2;
    int r = idx / S2;
    int oy = r % S2;
    int bc = r / S2;
    const float* src = yin + (size_t)bc * S * S;
    float acc = 0.f;
#pragma unroll
    for (int py = 0; py < 2; ++py)
#pragma unroll
        for (int px = 0; px < 2; ++px) {
            int cy = 2 * oy + py, cx = 2 * ox + px;
#pragma unroll
            for (int dy = 0; dy < 3; ++dy) {
                int ay = cy + dy - 1;
                if (ay < 0 || ay >= S) continue;
#pragma unroll
                for (int dx = 0; dx < 3; ++dx) {
                    int ax = cx + dx - 1;
                    if (ax < 0 || ax >= S) continue;
                    acc += g1[dy] * g1[dx] * src[ay * S + ax];
                }
            }
        }
    outp[idx] = acc * 0.25f * gs;
}

// ---------------------------------------------------------------------------
// Kernel 5: whole head in one launch, HNB blocks + software grid barrier.
// Stages: A res_block+mean -> h | B t1 | C h1 | D t3 | E h2 | F lat
// Each block owns an output-column slice with FULL K (no atomics).
// ---------------------------------------------------------------------------
__global__ __launch_bounds__(256) void head_kernel(
    const float* __restrict__ emb6,
    const float* __restrict__ w0, const float* __restrict__ b0,
    const float* __restrict__ w1, const float* __restrict__ b1,
    const float* __restrict__ l1_sw, const float* __restrict__ l1_sb,
    const float* __restrict__ l1_w1, const float* __restrict__ l1_b1,
    const float* __restrict__ l1_w2, const float* __restrict__ l1_b2,
    const float* __restrict__ l2_w1, const float* __restrict__ l2_b1,
    const float* __restrict__ l2_w2, const float* __restrict__ l2_b2,
    const float* __restrict__ lo_w, const float* __restrict__ lo_b,
    float* __restrict__ hbuf, float* __restrict__ t1buf,
    float* __restrict__ h1buf, float* __restrict__ t3buf,
    float* __restrict__ h2buf, int* __restrict__ bar,
    float* __restrict__ lat)
{
    __shared__ float smem[8192 + 512];
    const int bk = blockIdx.x, t = threadIdx.x;

    // ---- Stage A: res_block(outrb) + spatial mean (blocks 0-7) ----
    if (bk < 8) {
        float* sm_t = smem;
        float* sm_v = smem + 256;
        float* sm_r = smem + 512;
        sm_t[t] = emb6[bk * 256 + t];  // [c*4 + p]
        __syncthreads();
        {
            int o = t & 63, p = t >> 6;
            float a = 0.f;
            for (int k = 0; k < 64; ++k) a += w0[o * 64 + k] * lrelu(sm_t[k * 4 + p]);
            sm_v[o * 4 + p] = lrelu(a + b0[o]);
        }
        __syncthreads();
        {
            int o = t & 63, p = t >> 6;
            float a = 0.f;
            for (int k = 0; k < 64; ++k) a += w1[o * 64 + k] * sm_v[k * 4 + p];
            sm_r[o * 4 + p] = sm_t[o * 4 + p] + 0.1f * (a + b1[o]);
        }
        __syncthreads();
        if (t < 64)
            hbuf[bk * 64 + t] = 0.25f * (sm_r[t * 4] + sm_r[t * 4 + 1] + sm_r[t * 4 + 2] + sm_r[t * 4 + 3]);
    }
    grid_barrier(bar, 1);

    // ---- Stage B: t1[8][1024] = lrelu(lrelu(h) @ l1_w1 + l1_b1), 64 cols/block ----
    {
        float* s_h = smem;  // 512
        for (int j = t; j < 512; j += 256) s_h[j] = lrelu(hbuf[j]);
        __syncthreads();
        int col = bk * 64 + (t & 63);
        int b4 = t >> 6;  // handles b4 and b4+4
        float a0 = 0.f, a1 = 0.f;
        for (int k = 0; k < 64; ++k) {
            float wv = l1_w1[k * 1024 + col];
            a0 += s_h[b4 * 64 + k] * wv;
            a1 += s_h[(b4 + 4) * 64 + k] * wv;
        }
        float bi = l1_b1[col];
        t1buf[b4 * 1024 + col] = lrelu(a0 + bi);
        t1buf[(b4 + 4) * 1024 + col] = lrelu(a1 + bi);
    }
    grid_barrier(bar, 2);

    // ---- Stage C: h1 = (h @ l1_sw + l1_sb) + 0.1*(t1 @ l1_w2 + l1_b2), 32 cols/block ----
    {
        float* s_t1 = smem;        // 8192
        float* s_hr = smem + 8192; // 512 (raw h)
        for (int j = t; j < 8192; j += 256) s_t1[j] = t1buf[j];
        for (int j = t; j < 512; j += 256) s_hr[j] = hbuf[j];
        __syncthreads();
        int gcol = bk * 32 + (t & 31), b = t >> 5;
        float acc = 0.f;
        for (int k = 0; k < 1024; ++k) acc += s_t1[b * 1024 + k] * l1_w2[k * 512 + gcol];
        float accs = 0.f;
        for (int k = 0; k < 64; ++k) accs += s_hr[b * 64 + k] * l1_sw[k * 512 + gcol];
        h1buf[b * 512 + gcol] = accs + l1_sb[gcol] + 0.1f * (acc + l1_b2[gcol]);
    }
    grid_barrier(bar, 3);

    // ---- Stage D: t3 = lrelu(lrelu(h1) @ l2_w1 + l2_b1), 32 cols/block ----
    {
        float* s_u = smem;  // 4096
        for (int j = t; j < 4096; j += 256) s_u[j] = lrelu(h1buf[j]);
        __syncthreads();
        int gcol = bk * 32 + (t & 31), b = t >> 5;
        float acc = 0.f;
        for (int k = 0; k < 512; ++k) acc += s_u[b * 512 + k] * l2_w1[k * 512 + gcol];
        t3buf[b * 512 + gcol] = lrelu(acc + l2_b1[gcol]);
    }
    grid_barrier(bar, 4);

    // ---- Stage E: h2 = h1 + 0.1*(t3 @ l2_w2 + l2_b2) ----
    {
        float* s_u = smem;
        for (int j = t; j < 4096; j += 256) s_u[j] = t3buf[j];
        __syncthreads();
        int gcol = bk * 32 + (t & 31), b = t >> 5;
        float acc = 0.f;
        for (int k = 0; k < 512; ++k) acc += s_u[b * 512 + k] * l2_w2[k * 512 + gcol];
        h2buf[b * 512 + gcol] = h1buf[b * 512 + gcol] + 0.1f * (acc + l2_b2[gcol]);
    }
    grid_barrier(bar, 5);

    // ---- Stage F: lat = h2 @ lo_w + lo_b ----
    {
        float* s_u = smem;
        for (int j = t; j < 4096; j += 256) s_u[j] = h2buf[j];
        __syncthreads();
        int gcol = bk * 32 + (t & 31), b = t >> 5;
        float acc = 0.f;
        for (int k = 0; k < 512; ++k) acc += s_u[b * 512 + k] * lo_w[k * 512 + gcol];
        lat[b * 512 + gcol] = acc + lo_b[gcol];
    }
}

// ---------------------------------------------------------------------------
extern "C" void kernel_launch(void* const* d_in, const int* in_sizes, int n_in,
                              void* d_out, int out_size, void* d_ws, size_t ws_size,
                              hipStream_t stream) {
    const float* x      = (const float*)d_in[0];
    const float* inj    = (const float*)d_in[1];
    const float* leak   = (const float*)d_in[2];
    const float* in_w   = (const float*)d_in[3];
    const float* in_b   = (const float*)d_in[4];
    const float* inrb_w0 = (const float*)d_in[5];
    const float* inrb_b0 = (const float*)d_in[6];
    const float* inrb_w1 = (const float*)d_in[7];
    const float* inrb_b1 = (const float*)d_in[8];
    const float* hyp_w  = (const float*)d_in[9];
    const float* hyp_b  = (const float*)d_in[10];
    const float* outrb_w0 = (const float*)d_in[11];
    const float* outrb_b0 = (const float*)d_in[12];
    const float* outrb_w1 = (const float*)d_in[13];
    const float* outrb_b1 = (const float*)d_in[14];
    const float* l1_sw  = (const float*)d_in[15];
    const float* l1_sb  = (const float*)d_in[16];
    const float* l1_w1  = (const float*)d_in[17];
    const float* l1_b1  = (const float*)d_in[18];
    const float* l1_w2  = (const float*)d_in[19];
    const float* l1_b2  = (const float*)d_in[20];
    const float* l2_w1  = (const float*)d_in[21];
    const float* l2_b1  = (const float*)d_in[22];
    const float* l2_w2  = (const float*)d_in[23];
    const float* l2_b2  = (const float*)d_in[24];
    const float* lo_w   = (const float*)d_in[25];
    const float* lo_b   = (const float*)d_in[26];

    float* out = (float*)d_out;
    float* dyn = (float*)d_ws;
    float* ybuf = dyn + (size_t)BATCH * PT;
    short* dyn16 = (short*)(ybuf + (size_t)BATCH * 64 * 16384);
    float* hbuf = (float*)(dyn16 + (size_t)BATCH * PT);
    float* t1buf = hbuf + 512;
    float* h1buf = t1buf + 8192;
    float* t3buf = h1buf + 4096;
    float* h2buf = t3buf + 4096;
    int* bar = (int*)(h2buf + 4096);

    hyper_kernel<<<(PT + 255) / 256, 256, 0, stream>>>(inj, hyp_w, hyp_b, dyn, dyn16);

    size_t cur = 4096;
    stem_kernel<<<BATCH * 256, 256, 0, stream>>>(
        x, in_w, in_b, inrb_w0, inrb_b0, inrb_w1, inrb_b1, out + cur);

    int S = 128, sh = 7;
    for (int i = 0; i < 6; ++i) {
        if (S >= 64) {
            iter_kernel<4><<<BATCH * (S * S / 64), 256, 0, stream>>>(
                out + cur, dyn, dyn16, leak, ybuf, S, sh);
        } else {
            iter_kernel<1><<<BATCH * (S * S / 16), 256, 0, stream>>>(
                out + cur, dyn, dyn16, leak, ybuf, S, sh);
        }
        int S2 = S >> 1;
        int total = BATCH * 64 * S2 * S2;
        size_t nxt = cur + (size_t)BATCH * 64 * S * S;
        down_kernel<<<(total + 255) / 256, 256, 0, stream>>>(ybuf, out + nxt, S, total, bar);
        cur = nxt;
        S = S2; sh -= 1;
    }

    head_kernel<<<HNB, 256, 0, stream>>>(
        out + cur, outrb_w0, outrb_b0, outrb_w1, outrb_b1,
        l1_sw, l1_sb, l1_w1, l1_b1, l1_w2, l1_b2,
        l2_w1, l2_b1, l2_w2, l2_b2, lo_w, lo_b,
        hbuf, t1buf, h1buf, t3buf, h2buf, bar, out);
}